// Round 7
// baseline (591.594 us; speedup 1.0000x reference)
//
#include <hip/hip_runtime.h>
#include <stdint.h>

// ---------------- common types / helpers ----------------

typedef short bf16x8 __attribute__((ext_vector_type(8)));
typedef float f32x4 __attribute__((ext_vector_type(4)));

struct alignas(8) us4 { unsigned short x, y, z, w; };

__device__ __forceinline__ unsigned short f32_to_bf16(float f) {
  union { float f; uint32_t u; } v; v.f = f;
  uint32_t u = v.u;
  uint32_t r = (u + 0x7fffu + ((u >> 16) & 1u)) >> 16;  // RNE
  return (unsigned short)r;
}

__device__ __forceinline__ float bf16_to_f32(unsigned short h) {
  union { uint32_t u; float f; } v; v.u = ((uint32_t)h) << 16;
  return v.f;
}

// pack two f32 into bf16x2 by truncation: one v_perm_b32
__device__ __forceinline__ uint32_t pack_bf16_trunc(float lo, float hi) {
  union { float f; uint32_t u; } a, b; a.f = lo; b.f = hi;
  return __builtin_amdgcn_perm(b.u, a.u, 0x07060302u);  // [lo.hi16, hi.hi16]
}

// async global->LDS, 16B per lane; LDS dest is wave-uniform base + lane*16
__device__ __forceinline__ void g2l16(const unsigned short* g, unsigned short* l) {
  __builtin_amdgcn_global_load_lds((__attribute__((address_space(1))) void*)g,
                                   (__attribute__((address_space(3))) void*)l,
                                   16, 0, 0);
}

// stage one 96x96 pre-swizzled weight image (1152 granules) linearly
__device__ __forceinline__ void stageW(const unsigned short* __restrict__ src,
                                       unsigned short* dst, int w, int lane) {
#pragma unroll
  for (int it = 0; it < 4; ++it)
    g2l16(src + (size_t)((it * 4 + w) * 64 + lane) * 8, &dst[(it * 4 + w) * 512]);
  if (w < 2)
    g2l16(src + (size_t)((16 + w) * 64 + lane) * 8, &dst[(16 + w) * 512]);
}

// ---------------- problem constants ----------------
// B=128, S=512, D=768, NH=8, HD=96, HID=384

#define N_X   50331648   // 128*512*768
#define N_P   589824     // 8*96*768
#define N_W1  294912     // 8*384*96
#define N_W2  294912     // 8*96*384
#define N_HI  50331648   // 8*128*512*96  (plane-blocked: [hd*128+b][kb][s][32])

// ---------------- kernel 0: merged prologue ----------------
// One dispatch: cast X (49152 blocks), cast P (576), repack W1 (32), W2 (32).
// Saves 3 launch gaps; bodies identical to the R5 kernels.

__global__ __launch_bounds__(256) void prep(
    const float* __restrict__ X, const float* __restrict__ P,
    const float* __restrict__ W1, const float* __restrict__ W2,
    unsigned short* __restrict__ Xbf, unsigned short* __restrict__ Pbf,
    unsigned short* __restrict__ W1bf, unsigned short* __restrict__ W2bf) {
  const int bx = blockIdx.x;
  const int tid = threadIdx.x;
  if (bx < 49152) {            // cast X: exact, no bounds check (49152*256 = N_X/4)
    const int idx = bx * 256 + tid;
    float4 v = ((const float4*)X)[idx];
    us4 o = {f32_to_bf16(v.x), f32_to_bf16(v.y), f32_to_bf16(v.z), f32_to_bf16(v.w)};
    ((us4*)Xbf)[idx] = o;
  } else if (bx < 49728) {     // cast P: 576 blocks exact (576*256 = N_P/4)
    const int idx = (bx - 49152) * 256 + tid;
    float4 v = ((const float4*)P)[idx];
    us4 o = {f32_to_bf16(v.x), f32_to_bf16(v.y), f32_to_bf16(v.z), f32_to_bf16(v.w)};
    ((us4*)Pbf)[idx] = o;
  } else if (bx < 49760) {     // repack W1, quarter = hd*4+ph
    const int quarter = bx - 49728;
    const int hd = quarter >> 2, ph = quarter & 3;
    for (int t = tid; t < 1152; t += 256) {
      const int kb = t / 384;
      const int rem = t - kb * 384;
      const int f = rem >> 2, slot = rem & 3;
      const int pos = slot ^ ((f >> 1) & 3);
      const float* src =
          W1 + ((size_t)(hd * 384 + ph * 96 + f)) * 96 + kb * 32 + pos * 8;
      float4 a = *(const float4*)src;
      float4 b = *(const float4*)(src + 4);
      us4 o1 = {f32_to_bf16(a.x), f32_to_bf16(a.y), f32_to_bf16(a.z), f32_to_bf16(a.w)};
      us4 o2 = {f32_to_bf16(b.x), f32_to_bf16(b.y), f32_to_bf16(b.z), f32_to_bf16(b.w)};
      us4* dst = (us4*)(W1bf + (size_t)quarter * 9216 + t * 8);
      dst[0] = o1;
      dst[1] = o2;
    }
  } else {                     // repack W2
    const int quarter = bx - 49760;
    const int hd = quarter >> 2, ph = quarter & 3;
    for (int t = tid; t < 1152; t += 256) {
      const int kb = t / 384;
      const int rem = t - kb * 384;
      const int h = rem >> 2, slot = rem & 3;
      const int pos = slot ^ ((h >> 1) & 3);
      const float* src =
          W2 + ((size_t)(hd * 96 + h)) * 384 + ph * 96 + kb * 32 + pos * 8;
      float4 a = *(const float4*)src;
      float4 b = *(const float4*)(src + 4);
      us4 o1 = {f32_to_bf16(a.x), f32_to_bf16(a.y), f32_to_bf16(a.z), f32_to_bf16(a.w)};
      us4 o2 = {f32_to_bf16(b.x), f32_to_bf16(b.y), f32_to_bf16(b.z), f32_to_bf16(b.w)};
      us4* dst = (us4*)(W2bf + (size_t)quarter * 9216 + t * 8);
      dst[0] = o1;
      dst[1] = o2;
    }
  }
}

// ---------------- kernel 1: Hi = X @ P^T + bP (plane-blocked output) ----------------
// XCD-aware remap (T1, proven R5) + As/Bs granule swizzle via pre-swizzled
// sources. Epilogue writes Hi plane-blocked: [hd*128+b][kb=h>>5][s][h&31].
// (unchanged from R5)

__global__ __launch_bounds__(256) void gemm_hi(
    const unsigned short* __restrict__ Xbf,
    const unsigned short* __restrict__ Pbf,
    const float* __restrict__ bP,
    unsigned short* __restrict__ Hi) {
  __shared__ __align__(16) unsigned short As[128 * 32];
  __shared__ __align__(16) unsigned short Bs[128 * 32];

  const int tid = threadIdx.x;
  const int w = tid >> 6;
  const int lane = tid & 63;
  const int r = lane & 15;
  const int q = lane >> 4;

  const int hwid = blockIdx.x;                      // 0..3071
  const int wkid = (hwid & 7) * 384 + (hwid >> 3);  // per-XCD contiguous chunk
  const int bn = wkid % 6;   // 0..5
  const int bm = wkid / 6;   // 0..511

  const int wr = w >> 1, wc = w & 1;
  const int psw = q ^ ((r >> 1) & 3);  // swizzled read granule

  f32x4 acc[4][4];
#pragma unroll
  for (int a = 0; a < 4; ++a)
#pragma unroll
    for (int c = 0; c < 4; ++c) acc[a][c] = (f32x4){0.f, 0.f, 0.f, 0.f};

  const int ldr = lane >> 2;
  const int ldc = ((lane & 3) ^ ((lane >> 3) & 3)) * 8;
  const unsigned short* Abase = Xbf + (size_t)(bm * 128) * 768 + ldc;
  const unsigned short* Bbase = Pbf + (size_t)(bn * 128) * 768 + ldc;

  for (int k0 = 0; k0 < 768; k0 += 32) {
    __syncthreads();
    g2l16(Abase + (size_t)(w * 16 + ldr) * 768 + k0, &As[w * 512]);
    g2l16(Abase + (size_t)(64 + w * 16 + ldr) * 768 + k0, &As[(4 + w) * 512]);
    g2l16(Bbase + (size_t)(w * 16 + ldr) * 768 + k0, &Bs[w * 512]);
    g2l16(Bbase + (size_t)(64 + w * 16 + ldr) * 768 + k0, &Bs[(4 + w) * 512]);
    __syncthreads();

    bf16x8 af[4], bfr[4];
#pragma unroll
    for (int t = 0; t < 4; ++t)
      af[t] = *(const bf16x8*)&As[(wr * 64 + t * 16 + r) * 32 + psw * 8];
#pragma unroll
    for (int t = 0; t < 4; ++t)
      bfr[t] = *(const bf16x8*)&Bs[(wc * 64 + t * 16 + r) * 32 + psw * 8];
#pragma unroll
    for (int mt = 0; mt < 4; ++mt)
#pragma unroll
      for (int nt = 0; nt < 4; ++nt)
        acc[mt][nt] = __builtin_amdgcn_mfma_f32_16x16x32_bf16(
            af[mt], bfr[nt], acc[mt][nt], 0, 0, 0);
  }

  const int bb = bm >> 2;
  const int sb = (bm & 3) * 128 + wr * 64;
#pragma unroll
  for (int nt = 0; nt < 4; ++nt) {
    const int n0 = bn * 128 + wc * 64 + nt * 16;
    const int hd = n0 / 96;
    const int hloc = n0 - hd * 96;       // multiple of 16
    const int kb = hloc >> 5;            // plane, const per nt
    const int col = (hloc & 31) + r;     // within-plane column
    const float bias = bP[n0 + r];
    unsigned short* obase =
        Hi + (size_t)(hd * 128 + bb) * 49152 + kb * 16384 + col;
#pragma unroll
    for (int mt = 0; mt < 4; ++mt) {
#pragma unroll
      for (int rg = 0; rg < 4; ++rg) {
        const int s = sb + mt * 16 + q * 4 + rg;
        obase[(size_t)s * 32] = f32_to_bf16(acc[mt][nt][rg] + bias);
      }
    }
  }
}

// ---------------- kernel 2: fused per-head MLP -> logits -> softmax -> pool ----------------
// v9: occupancy-first restructure (R6 lesson: barriers drain all flights ->
// source-level async is nullified; the only latency hider is TLP).
//  * Ys LDS tile DROPPED. GEMM2 B-frags loaded transiently from plane-blocked
//    Hi (L2) inside GEMM2 -- no persistent caching (R2/R6 spill lesson).
//    Pooling reads Y scalar from global/L2 once per chunk.
//  * U region (26.6KB) aliases W1 image (first 18KB) and F (pad-104):
//    W1 dead after GEMM2 (barrier C), F written after C, read after D.
//  * W1+W2 staged together at phase top -> ONE merged drain per phase.
//  * LDS ~51KB -> 3 blocks/CU (12 waves/CU vs R5's 8). launch_bounds(256,3)
//    caps VGPR at 170 (current live peak ~140 -> no spill expected; sentinel:
//    WRITE_SIZE must stay ~384KB).

__global__ __launch_bounds__(256, 3) void mlp_pool(
    const unsigned short* __restrict__ Hi,    // plane-blocked
    const unsigned short* __restrict__ W1bf,  // [(hd,ph)][kb][f][32] pre-swizzled
    const unsigned short* __restrict__ W2bf,  // [(hd,ph)][kb][h][32] pre-swizzled
    const float* __restrict__ b1,             // 8*384
    const float* __restrict__ b2,             // 8*96
    const float* __restrict__ mask,           // B x S
    float* __restrict__ out) {                // B x 768
  __shared__ __align__(16) unsigned short U[128 * 104];   // W1 image (9216) / F pad-104
  __shared__ __align__(16) unsigned short Ws2[3 * 96 * 32];  // W2q [kb][h][32] swz
  __shared__ __align__(16) float b1s[384];
  __shared__ __align__(16) float b2s[96];
  __shared__ float bias_s[512];
  __shared__ float redA[4][96];
  __shared__ float redB[4][96];

  const int x = blockIdx.x;
  const int b = x & 127;    // batch
  const int hd = x >> 7;    // head (slowest -> weight L2 sharing)

  const int tid = threadIdx.x;
  const int w = tid >> 6;
  const int lane = tid & 63;
  const int r = lane & 15;
  const int q = lane >> 4;
  const int psw = q ^ ((r >> 1) & 3);  // swizzled read granule

  if (tid < 96) b2s[tid] = b2[hd * 96 + tid];
  for (int i = tid; i < 384; i += 256) b1s[i] = b1[hd * 384 + i];
  for (int s = tid; s < 512; s += 256)
    bias_s[s] = mask[b * 512 + s] > 0.5f ? 0.f : -1e30f;

  float m_run[6], l_run[6], v_run[6];
#pragma unroll
  for (int nt = 0; nt < 6; ++nt) { m_run[nt] = -3e30f; l_run[nt] = 0.f; v_run[nt] = 0.f; }

  const unsigned short* ysrc = Hi + (size_t)(hd * 128 + b) * 49152;
  const unsigned short* w1h = W1bf + (size_t)(hd * 4) * 9216;
  const unsigned short* w2h = W2bf + (size_t)(hd * 4) * 9216;

  for (int c = 0; c < 4; ++c) {
    const unsigned short* yc = ysrc + c * 4096;

    f32x4 acc3[2][6];
#pragma unroll
    for (int sp = 0; sp < 2; ++sp)
#pragma unroll
      for (int nt = 0; nt < 6; ++nt) acc3[sp][nt] = (f32x4){0.f, 0.f, 0.f, 0.f};

    for (int ph = 0; ph < 4; ++ph) {
      if (c | ph) __syncthreads();  // A: prev GEMM3 done with U(F)/Ws2
      // stage W1(ph)->U and W2(ph)->Ws2: one merged flight, one drain at B
      stageW(w1h + ph * 9216, U, w, lane);
      stageW(w2h + ph * 9216, Ws2, w, lane);
      __syncthreads();  // B: W1+W2 ready (also bias/b1s visible on first iter)

      // GEMM2: F^T = W1q @ Y^T. M=96(f), N=128(s), K=96.
      // Y B-frags transient from global (L2); A-frags from U (W1 image).
      f32x4 acc2[6][2];
#pragma unroll
      for (int ft = 0; ft < 6; ++ft)
#pragma unroll
        for (int sp = 0; sp < 2; ++sp) acc2[ft][sp] = (f32x4){0.f, 0.f, 0.f, 0.f};
#pragma unroll
      for (int kb = 0; kb < 3; ++kb) {
        bf16x8 bfrg[2];
#pragma unroll
        for (int sp = 0; sp < 2; ++sp)
          bfrg[sp] = *(const bf16x8*)(yc + kb * 16384 +
                                      ((w * 2 + sp) * 16 + r) * 32 + q * 8);
#pragma unroll
        for (int ft = 0; ft < 6; ++ft) {
          bf16x8 afrg = *(const bf16x8*)&U[kb * 3072 + (ft * 16 + r) * 32 + psw * 8];
#pragma unroll
          for (int sp = 0; sp < 2; ++sp)
            acc2[ft][sp] = __builtin_amdgcn_mfma_f32_16x16x32_bf16(
                afrg, bfrg[sp], acc2[ft][sp], 0, 0, 0);
        }
      }
      __syncthreads();  // C: W1 consumed -> U free for F

      // epilogue: +b1, relu, pack pairs, b64 write F into U ([s][104] pad layout)
#pragma unroll
      for (int ft = 0; ft < 6; ++ft) {
        float4 bv = *(const float4*)&b1s[ph * 96 + ft * 16 + q * 4];
#pragma unroll
        for (int sp = 0; sp < 2; ++sp) {
          const int s = (w * 2 + sp) * 16 + r;
          float v0 = fmaxf(acc2[ft][sp][0] + bv.x, 0.f);
          float v1 = fmaxf(acc2[ft][sp][1] + bv.y, 0.f);
          float v2 = fmaxf(acc2[ft][sp][2] + bv.z, 0.f);
          float v3 = fmaxf(acc2[ft][sp][3] + bv.w, 0.f);
          uint2 pk;
          pk.x = pack_bf16_trunc(v0, v1);
          pk.y = pack_bf16_trunc(v2, v3);
          *(uint2*)((uint32_t*)&U[0] + s * 52 + ft * 8 + q * 2) = pk;
        }
      }
      __syncthreads();  // D: F ready

      // GEMM3 partial: M=128(s), N=96(h), K=96 this phase.
#pragma unroll
      for (int kb = 0; kb < 3; ++kb) {
        bf16x8 afrg[2];
#pragma unroll
        for (int sp = 0; sp < 2; ++sp)
          afrg[sp] = *(const bf16x8*)&U[((w * 2 + sp) * 16 + r) * 104 + kb * 32 + q * 8];
#pragma unroll
        for (int nt = 0; nt < 6; ++nt) {
          bf16x8 bfrg2 = *(const bf16x8*)&Ws2[kb * 3072 + (nt * 16 + r) * 32 + psw * 8];
#pragma unroll
          for (int sp = 0; sp < 2; ++sp)
            acc3[sp][nt] = __builtin_amdgcn_mfma_f32_16x16x32_bf16(
                afrg[sp], bfrg2, acc3[sp][nt], 0, 0, 0);
        }
      }
    }

    // ---- chunk pooling: online softmax accumulate (Y from global/L2) ----
    // C-layout: h = nt*16 + r, s_local = (w*2+sp)*16 + q*4 + rg
#pragma unroll
    for (int nt = 0; nt < 6; ++nt) {
      const float b2v = b2s[nt * 16 + r];
      float lm = -3e30f;
#pragma unroll
      for (int sp = 0; sp < 2; ++sp) {
#pragma unroll
        for (int rg = 0; rg < 4; ++rg) {
          const int sl = (w * 2 + sp) * 16 + q * 4 + rg;
          float lg = acc3[sp][nt][rg] + b2v + bias_s[c * 128 + sl];
          lm = fmaxf(lm, lg);
        }
      }
      lm = fmaxf(lm, __shfl_xor(lm, 16));
      lm = fmaxf(lm, __shfl_xor(lm, 32));
      if (q == 0) redA[w][nt * 16 + r] = lm;
    }
    __syncthreads();  // chunk-max ready across waves
#pragma unroll
    for (int nt = 0; nt < 6; ++nt) {
      const int h = nt * 16 + r;
      // plane-blocked global Y: col h&31 = (nt&1)*16 + r, plane = nt>>1
      const unsigned short* yb = yc + (nt >> 1) * 16384 + (nt & 1) * 16 + r;
      const float cm = fmaxf(fmaxf(redA[0][h], redA[1][h]),
                             fmaxf(redA[2][h], redA[3][h]));
      const float mnew = fmaxf(m_run[nt], cm);
      const float sc = __expf(m_run[nt] - mnew);
      m_run[nt] = mnew;
      float lacc = l_run[nt] * sc;
      float vacc = v_run[nt] * sc;
      const float b2v = b2s[h];
#pragma unroll
      for (int sp = 0; sp < 2; ++sp) {
#pragma unroll
        for (int rg = 0; rg < 4; ++rg) {
          const int sl = (w * 2 + sp) * 16 + q * 4 + rg;
          float lg = acc3[sp][nt][rg] + b2v + bias_s[c * 128 + sl];
          float e = __expf(lg - mnew);
          lacc += e;
          vacc += e * bf16_to_f32(yb[(size_t)sl * 32]);
        }
      }
      l_run[nt] = lacc;
      v_run[nt] = vacc;
    }
  }

  // ---- final reduce: sum l,v across q-groups then waves; out = v/l ----
  __syncthreads();  // redA/redB free
#pragma unroll
  for (int nt = 0; nt < 6; ++nt) {
    float ls = l_run[nt], vs = v_run[nt];
    ls += __shfl_xor(ls, 16);
    vs += __shfl_xor(vs, 16);
    ls += __shfl_xor(ls, 32);
    vs += __shfl_xor(vs, 32);
    if (q == 0) {
      redA[w][nt * 16 + r] = ls;
      redB[w][nt * 16 + r] = vs;
    }
  }
  __syncthreads();
  if (tid < 96) {
    float ls = redA[0][tid] + redA[1][tid] + redA[2][tid] + redA[3][tid];
    float vs = redB[0][tid] + redB[1][tid] + redB[2][tid] + redB[3][tid];
    out[(size_t)b * 768 + hd * 96 + tid] = vs / ls;
  }
}

// ---------------- launcher ----------------

extern "C" void kernel_launch(void* const* d_in, const int* in_sizes, int n_in,
                              void* d_out, int out_size, void* d_ws, size_t ws_size,
                              hipStream_t stream) {
  const float* X    = (const float*)d_in[0];
  const float* mask = (const float*)d_in[1];
  const float* P    = (const float*)d_in[2];
  const float* bP   = (const float*)d_in[3];
  const float* W1   = (const float*)d_in[4];
  const float* b1   = (const float*)d_in[5];
  const float* W2   = (const float*)d_in[6];
  const float* b2   = (const float*)d_in[7];
  float* out = (float*)d_out;
  (void)in_sizes; (void)n_in; (void)out_size; (void)ws_size;

  unsigned short* Xbf  = (unsigned short*)d_ws;
  unsigned short* Pbf  = Xbf + N_X;
  unsigned short* W1bf = Pbf + N_P;
  unsigned short* W2bf = W1bf + N_W1;
  unsigned short* Hi   = W2bf + N_W2;

  prep<<<49792, 256, 0, stream>>>(X, P, W1, W2, Xbf, Pbf, W1bf, W2bf);
  gemm_hi<<<3072, 256, 0, stream>>>(Xbf, Pbf, bP, Hi);
  mlp_pool<<<8 * 128, 256, 0, stream>>>(Hi, W1bf, W2bf, b1, b2, mask, out);
}

// Round 8
// 539.159 us; speedup vs baseline: 1.0973x; 1.0973x over previous
//
#include <hip/hip_runtime.h>
#include <stdint.h>

// ---------------- common types / helpers ----------------

typedef short bf16x8 __attribute__((ext_vector_type(8)));
typedef float f32x4 __attribute__((ext_vector_type(4)));

struct alignas(8) us4 { unsigned short x, y, z, w; };

__device__ __forceinline__ unsigned short f32_to_bf16(float f) {
  union { float f; uint32_t u; } v; v.f = f;
  uint32_t u = v.u;
  uint32_t r = (u + 0x7fffu + ((u >> 16) & 1u)) >> 16;  // RNE
  return (unsigned short)r;
}

__device__ __forceinline__ float bf16_to_f32(unsigned short h) {
  union { uint32_t u; float f; } v; v.u = ((uint32_t)h) << 16;
  return v.f;
}

// pack two f32 into bf16x2 by truncation: one v_perm_b32
__device__ __forceinline__ uint32_t pack_bf16_trunc(float lo, float hi) {
  union { float f; uint32_t u; } a, b; a.f = lo; b.f = hi;
  return __builtin_amdgcn_perm(b.u, a.u, 0x07060302u);  // [lo.hi16, hi.hi16]
}

// async global->LDS, 16B per lane; LDS dest is wave-uniform base + lane*16
__device__ __forceinline__ void g2l16(const unsigned short* g, unsigned short* l) {
  __builtin_amdgcn_global_load_lds((__attribute__((address_space(1))) void*)g,
                                   (__attribute__((address_space(3))) void*)l,
                                   16, 0, 0);
}

// stage one 96x96 pre-swizzled weight image (1152 granules) linearly
__device__ __forceinline__ void stageW(const unsigned short* __restrict__ src,
                                       unsigned short* dst, int w, int lane) {
#pragma unroll
  for (int it = 0; it < 4; ++it)
    g2l16(src + (size_t)((it * 4 + w) * 64 + lane) * 8, &dst[(it * 4 + w) * 512]);
  if (w < 2)
    g2l16(src + (size_t)((16 + w) * 64 + lane) * 8, &dst[(16 + w) * 512]);
}

// ---------------- problem constants ----------------
// B=128, S=512, D=768, NH=8, HD=96, HID=384

#define N_X   50331648   // 128*512*768
#define N_P   589824     // 8*96*768
#define N_W1  294912     // 8*384*96
#define N_W2  294912     // 8*96*384
#define N_HI  50331648   // 8*128*512*96  (plane-blocked: [hd*128+b][kb][s][32])

// ---------------- kernel 0: merged prologue (proven R7) ----------------

__global__ __launch_bounds__(256) void prep(
    const float* __restrict__ X, const float* __restrict__ P,
    const float* __restrict__ W1, const float* __restrict__ W2,
    unsigned short* __restrict__ Xbf, unsigned short* __restrict__ Pbf,
    unsigned short* __restrict__ W1bf, unsigned short* __restrict__ W2bf) {
  const int bx = blockIdx.x;
  const int tid = threadIdx.x;
  if (bx < 49152) {            // cast X (49152*256 = N_X/4)
    const int idx = bx * 256 + tid;
    float4 v = ((const float4*)X)[idx];
    us4 o = {f32_to_bf16(v.x), f32_to_bf16(v.y), f32_to_bf16(v.z), f32_to_bf16(v.w)};
    ((us4*)Xbf)[idx] = o;
  } else if (bx < 49728) {     // cast P (576*256 = N_P/4)
    const int idx = (bx - 49152) * 256 + tid;
    float4 v = ((const float4*)P)[idx];
    us4 o = {f32_to_bf16(v.x), f32_to_bf16(v.y), f32_to_bf16(v.z), f32_to_bf16(v.w)};
    ((us4*)Pbf)[idx] = o;
  } else if (bx < 49760) {     // repack W1
    const int quarter = bx - 49728;
    const int hd = quarter >> 2, ph = quarter & 3;
    for (int t = tid; t < 1152; t += 256) {
      const int kb = t / 384;
      const int rem = t - kb * 384;
      const int f = rem >> 2, slot = rem & 3;
      const int pos = slot ^ ((f >> 1) & 3);
      const float* src =
          W1 + ((size_t)(hd * 384 + ph * 96 + f)) * 96 + kb * 32 + pos * 8;
      float4 a = *(const float4*)src;
      float4 b = *(const float4*)(src + 4);
      us4 o1 = {f32_to_bf16(a.x), f32_to_bf16(a.y), f32_to_bf16(a.z), f32_to_bf16(a.w)};
      us4 o2 = {f32_to_bf16(b.x), f32_to_bf16(b.y), f32_to_bf16(b.z), f32_to_bf16(b.w)};
      us4* dst = (us4*)(W1bf + (size_t)quarter * 9216 + t * 8);
      dst[0] = o1;
      dst[1] = o2;
    }
  } else {                     // repack W2
    const int quarter = bx - 49760;
    const int hd = quarter >> 2, ph = quarter & 3;
    for (int t = tid; t < 1152; t += 256) {
      const int kb = t / 384;
      const int rem = t - kb * 384;
      const int h = rem >> 2, slot = rem & 3;
      const int pos = slot ^ ((h >> 1) & 3);
      const float* src =
          W2 + ((size_t)(hd * 96 + h)) * 384 + ph * 96 + kb * 32 + pos * 8;
      float4 a = *(const float4*)src;
      float4 b = *(const float4*)(src + 4);
      us4 o1 = {f32_to_bf16(a.x), f32_to_bf16(a.y), f32_to_bf16(a.z), f32_to_bf16(a.w)};
      us4 o2 = {f32_to_bf16(b.x), f32_to_bf16(b.y), f32_to_bf16(b.z), f32_to_bf16(b.w)};
      us4* dst = (us4*)(W2bf + (size_t)quarter * 9216 + t * 8);
      dst[0] = o1;
      dst[1] = o2;
    }
  }
}

// ---------------- kernel 1: Hi = X @ P^T + bP (plane-blocked, T1) ----------------
// (unchanged from R5)

__global__ __launch_bounds__(256) void gemm_hi(
    const unsigned short* __restrict__ Xbf,
    const unsigned short* __restrict__ Pbf,
    const float* __restrict__ bP,
    unsigned short* __restrict__ Hi) {
  __shared__ __align__(16) unsigned short As[128 * 32];
  __shared__ __align__(16) unsigned short Bs[128 * 32];

  const int tid = threadIdx.x;
  const int w = tid >> 6;
  const int lane = tid & 63;
  const int r = lane & 15;
  const int q = lane >> 4;

  const int hwid = blockIdx.x;                      // 0..3071
  const int wkid = (hwid & 7) * 384 + (hwid >> 3);  // per-XCD contiguous chunk
  const int bn = wkid % 6;   // 0..5
  const int bm = wkid / 6;   // 0..511

  const int wr = w >> 1, wc = w & 1;
  const int psw = q ^ ((r >> 1) & 3);  // swizzled read granule

  f32x4 acc[4][4];
#pragma unroll
  for (int a = 0; a < 4; ++a)
#pragma unroll
    for (int c = 0; c < 4; ++c) acc[a][c] = (f32x4){0.f, 0.f, 0.f, 0.f};

  const int ldr = lane >> 2;
  const int ldc = ((lane & 3) ^ ((lane >> 3) & 3)) * 8;
  const unsigned short* Abase = Xbf + (size_t)(bm * 128) * 768 + ldc;
  const unsigned short* Bbase = Pbf + (size_t)(bn * 128) * 768 + ldc;

  for (int k0 = 0; k0 < 768; k0 += 32) {
    __syncthreads();
    g2l16(Abase + (size_t)(w * 16 + ldr) * 768 + k0, &As[w * 512]);
    g2l16(Abase + (size_t)(64 + w * 16 + ldr) * 768 + k0, &As[(4 + w) * 512]);
    g2l16(Bbase + (size_t)(w * 16 + ldr) * 768 + k0, &Bs[w * 512]);
    g2l16(Bbase + (size_t)(64 + w * 16 + ldr) * 768 + k0, &Bs[(4 + w) * 512]);
    __syncthreads();

    bf16x8 af[4], bfr[4];
#pragma unroll
    for (int t = 0; t < 4; ++t)
      af[t] = *(const bf16x8*)&As[(wr * 64 + t * 16 + r) * 32 + psw * 8];
#pragma unroll
    for (int t = 0; t < 4; ++t)
      bfr[t] = *(const bf16x8*)&Bs[(wc * 64 + t * 16 + r) * 32 + psw * 8];
#pragma unroll
    for (int mt = 0; mt < 4; ++mt)
#pragma unroll
      for (int nt = 0; nt < 4; ++nt)
        acc[mt][nt] = __builtin_amdgcn_mfma_f32_16x16x32_bf16(
            af[mt], bfr[nt], acc[mt][nt], 0, 0, 0);
  }

  const int bb = bm >> 2;
  const int sb = (bm & 3) * 128 + wr * 64;
#pragma unroll
  for (int nt = 0; nt < 4; ++nt) {
    const int n0 = bn * 128 + wc * 64 + nt * 16;
    const int hd = n0 / 96;
    const int hloc = n0 - hd * 96;       // multiple of 16
    const int kb = hloc >> 5;            // plane, const per nt
    const int col = (hloc & 31) + r;     // within-plane column
    const float bias = bP[n0 + r];
    unsigned short* obase =
        Hi + (size_t)(hd * 128 + bb) * 49152 + kb * 16384 + col;
#pragma unroll
    for (int mt = 0; mt < 4; ++mt) {
#pragma unroll
      for (int rg = 0; rg < 4; ++rg) {
        const int s = sb + mt * 16 + q * 4 + rg;
        obase[(size_t)s * 32] = f32_to_bf16(acc[mt][nt][rg] + bias);
      }
    }
  }
}

// ---------------- kernel 2: fused per-head MLP -> logits -> softmax -> pool ----------------
// v10 = R5 structure with F kept IN REGISTERS between GEMM2 and GEMM3.
//  * GEMM2 C-layout (col=s=lane&15, row=f=q*4+rg) and GEMM3 A-frag layout
//    (row=s=lane&15, k=f=q*8+j) share the lane<->s mapping; only the f
//    distribution over q-groups differs. Redistribution per (kb,sp):
//    8 __shfl + 4 selects (target lane (r,q), granule kb takes ft=2kb+(q>>1)
//    words from source lanes r+16*2(q&1) and +16). Verified element-wise.
//  * Numerics identical to R5 (bias+relu+pack_bf16_trunc).
//  * Fs LDS (26.6K) eliminated -> LDS 48.9KB -> 3 blocks/CU (12 waves), at
//    the proven (256,2) VGPR cap 128 (16 waves allowed). TLP +50% is the win
//    (R5 regime: latency-bound, nothing busy). Spill sentinel: WRITE_SIZE.

__global__ __launch_bounds__(256, 2) void mlp_pool(
    const unsigned short* __restrict__ Hi,    // plane-blocked
    const unsigned short* __restrict__ W1bf,  // [(hd,ph)][kb][f][32] pre-swizzled
    const unsigned short* __restrict__ W2bf,  // [(hd,ph)][kb][h][32] pre-swizzled
    const float* __restrict__ b1,             // 8*384
    const float* __restrict__ b2,             // 8*96
    const float* __restrict__ mask,           // B x S
    float* __restrict__ out) {                // B x 768
  __shared__ __align__(16) unsigned short Ys[3 * 128 * 32];  // [kb][s][32] swizzled
  __shared__ __align__(16) unsigned short Ws[96 * 96];       // W1q/W2q [kb][row][32] swz
  __shared__ __align__(16) float b1s[384];
  __shared__ __align__(16) float b2s[96];
  __shared__ float bias_s[512];
  __shared__ float redA[4][96];
  __shared__ float redB[4][96];

  const int x = blockIdx.x;
  const int b = x & 127;    // batch
  const int hd = x >> 7;    // head (slowest -> weight L2 sharing)

  const int tid = threadIdx.x;
  const int w = tid >> 6;
  const int lane = tid & 63;
  const int r = lane & 15;
  const int q = lane >> 4;
  const int psw = q ^ ((r >> 1) & 3);  // swizzled read granule
  // per-thread Ys source offset: granule permutation within each 64B third
  const int ysx = (tid ^ ((tid >> 3) & 3)) * 8;
  // shfl source lanes for the F redistribution
  const int ra = r + ((q & 1) << 5);   // r + 32*(q&1)
  const int rb = ra + 16;
  const bool qhi = q >= 2;             // pick odd ft

  if (tid < 96) b2s[tid] = b2[hd * 96 + tid];
  for (int i = tid; i < 384; i += 256) b1s[i] = b1[hd * 384 + i];
  for (int s = tid; s < 512; s += 256)
    bias_s[s] = mask[b * 512 + s] > 0.5f ? 0.f : -1e30f;

  float m_run[6], l_run[6], v_run[6];
#pragma unroll
  for (int nt = 0; nt < 6; ++nt) { m_run[nt] = -3e30f; l_run[nt] = 0.f; v_run[nt] = 0.f; }

  const unsigned short* ysrc = Hi + (size_t)(hd * 128 + b) * 49152;
  const unsigned short* w1h = W1bf + (size_t)(hd * 4) * 9216;
  const unsigned short* w2h = W2bf + (size_t)(hd * 4) * 9216;

  for (int c = 0; c < 4; ++c) {
    __syncthreads();  // pooling(c-1) done with Ys; GEMM3(prev) done with Ws

    // stage Y chunk (R5-verbatim: linear dest, pre-permuted source granules)
    {
      const unsigned short* yc0 = ysrc + c * 4096 + ysx;
      g2l16(yc0, &Ys[w * 512]);
      g2l16(yc0 + 2048, &Ys[(4 + w) * 512]);
      g2l16(yc0 + 16384, &Ys[(8 + w) * 512]);
      g2l16(yc0 + 18432, &Ys[(12 + w) * 512]);
      g2l16(yc0 + 32768, &Ys[(16 + w) * 512]);
      g2l16(yc0 + 34816, &Ys[(20 + w) * 512]);
    }

    f32x4 acc3[2][6];
#pragma unroll
    for (int sp = 0; sp < 2; ++sp)
#pragma unroll
      for (int nt = 0; nt < 6; ++nt) acc3[sp][nt] = (f32x4){0.f, 0.f, 0.f, 0.f};

    for (int ph = 0; ph < 4; ++ph) {
      if (ph) __syncthreads();  // A: GEMM3(ph-1) done reading Ws

      // stage W1(ph) -> Ws (linear copy of pre-swizzled image)
      stageW(w1h + ph * 9216, Ws, w, lane);
      __syncthreads();  // B: W1 ready (and Ys on ph==0)

      // GEMM2: F^T = W1q @ Y^T. M=96(f), N=128(s), K=96.
      f32x4 acc2[6][2];
#pragma unroll
      for (int ft = 0; ft < 6; ++ft)
#pragma unroll
        for (int sp = 0; sp < 2; ++sp) acc2[ft][sp] = (f32x4){0.f, 0.f, 0.f, 0.f};
#pragma unroll
      for (int kb = 0; kb < 3; ++kb) {
        bf16x8 bfrg[2];
#pragma unroll
        for (int sp = 0; sp < 2; ++sp)
          bfrg[sp] = *(const bf16x8*)&Ys[kb * 4096 + ((w * 2 + sp) * 16 + r) * 32 + psw * 8];
#pragma unroll
        for (int ft = 0; ft < 6; ++ft) {
          bf16x8 afrg = *(const bf16x8*)&Ws[kb * 3072 + (ft * 16 + r) * 32 + psw * 8];
#pragma unroll
          for (int sp = 0; sp < 2; ++sp)
            acc2[ft][sp] = __builtin_amdgcn_mfma_f32_16x16x32_bf16(
                afrg, bfrg[sp], acc2[ft][sp], 0, 0, 0);
        }
      }

      // in-register F: +b1, relu, pack bf16 pairs (pkw0=f{0,1}, pkw1=f{2,3} of
      // each lane's 4 f-values), then redistribute to GEMM3 A-frag granules.
      uint32_t pkw0[6][2], pkw1[6][2];
#pragma unroll
      for (int ft = 0; ft < 6; ++ft) {
        float4 bv = *(const float4*)&b1s[ph * 96 + ft * 16 + q * 4];
#pragma unroll
        for (int sp = 0; sp < 2; ++sp) {
          float v0 = fmaxf(acc2[ft][sp][0] + bv.x, 0.f);
          float v1 = fmaxf(acc2[ft][sp][1] + bv.y, 0.f);
          float v2 = fmaxf(acc2[ft][sp][2] + bv.z, 0.f);
          float v3 = fmaxf(acc2[ft][sp][3] + bv.w, 0.f);
          pkw0[ft][sp] = pack_bf16_trunc(v0, v1);
          pkw1[ft][sp] = pack_bf16_trunc(v2, v3);
        }
      }
      // redistribute: lane (r,q), granule kb <- ft = 2kb+(q>>1), source lanes
      // ra (qs=2(q&1)) and rb (qs+1); word order = ascending f.
      bf16x8 af_r[3][2];
#pragma unroll
      for (int kb = 0; kb < 3; ++kb) {
#pragma unroll
        for (int sp = 0; sp < 2; ++sp) {
          uint32_t a0 = __shfl(pkw0[2 * kb][sp], ra);
          uint32_t a1 = __shfl(pkw1[2 * kb][sp], ra);
          uint32_t a2 = __shfl(pkw0[2 * kb][sp], rb);
          uint32_t a3 = __shfl(pkw1[2 * kb][sp], rb);
          uint32_t c0 = __shfl(pkw0[2 * kb + 1][sp], ra);
          uint32_t c1 = __shfl(pkw1[2 * kb + 1][sp], ra);
          uint32_t c2 = __shfl(pkw0[2 * kb + 1][sp], rb);
          uint32_t c3 = __shfl(pkw1[2 * kb + 1][sp], rb);
          union { uint32_t u[4]; bf16x8 v; } fu;
          fu.u[0] = qhi ? c0 : a0;
          fu.u[1] = qhi ? c1 : a1;
          fu.u[2] = qhi ? c2 : a2;
          fu.u[3] = qhi ? c3 : a3;
          af_r[kb][sp] = fu.v;
        }
      }
      __syncthreads();  // C: all GEMM2 reads of Ws done -> Ws free

      // stage W2(ph) -> Ws
      stageW(w2h + ph * 9216, Ws, w, lane);
      __syncthreads();  // D: W2 ready

      // GEMM3 partial: M=128(s), N=96(h), K=96 this phase. A from registers.
#pragma unroll
      for (int kb = 0; kb < 3; ++kb) {
#pragma unroll
        for (int nt = 0; nt < 6; ++nt) {
          bf16x8 bfrg2 = *(const bf16x8*)&Ws[kb * 3072 + (nt * 16 + r) * 32 + psw * 8];
#pragma unroll
          for (int sp = 0; sp < 2; ++sp)
            acc3[sp][nt] = __builtin_amdgcn_mfma_f32_16x16x32_bf16(
                af_r[kb][sp], bfrg2, acc3[sp][nt], 0, 0, 0);
        }
      }
    }

    // ---- chunk pooling: online softmax accumulate (R5-verbatim) ----
#pragma unroll
    for (int nt = 0; nt < 6; ++nt) {
      const float b2v = b2s[nt * 16 + r];
      float lm = -3e30f;
#pragma unroll
      for (int sp = 0; sp < 2; ++sp) {
#pragma unroll
        for (int rg = 0; rg < 4; ++rg) {
          const int sl = (w * 2 + sp) * 16 + q * 4 + rg;
          float lg = acc3[sp][nt][rg] + b2v + bias_s[c * 128 + sl];
          lm = fmaxf(lm, lg);
        }
      }
      lm = fmaxf(lm, __shfl_xor(lm, 16));
      lm = fmaxf(lm, __shfl_xor(lm, 32));
      if (q == 0) redA[w][nt * 16 + r] = lm;
    }
    __syncthreads();  // chunk-max ready across waves
#pragma unroll
    for (int nt = 0; nt < 6; ++nt) {
      const int h = nt * 16 + r;
      const int kbh = nt >> 1;                  // h>>5
      const int gh = (nt * 2 + (r >> 3)) & 3;   // (h>>3)&3
      const int hlo = r & 7;
      const float cm = fmaxf(fmaxf(redA[0][h], redA[1][h]),
                             fmaxf(redA[2][h], redA[3][h]));
      const float mnew = fmaxf(m_run[nt], cm);
      const float sc = __expf(m_run[nt] - mnew);
      m_run[nt] = mnew;
      float lacc = l_run[nt] * sc;
      float vacc = v_run[nt] * sc;
      const float b2v = b2s[h];
#pragma unroll
      for (int sp = 0; sp < 2; ++sp) {
#pragma unroll
        for (int rg = 0; rg < 4; ++rg) {
          const int sl = (w * 2 + sp) * 16 + q * 4 + rg;
          float lg = acc3[sp][nt][rg] + b2v + bias_s[c * 128 + sl];
          float e = __expf(lg - mnew);
          lacc += e;
          const int pos = gh ^ ((sl >> 1) & 3);
          vacc += e * bf16_to_f32(Ys[kbh * 4096 + sl * 32 + pos * 8 + hlo]);
        }
      }
      l_run[nt] = lacc;
      v_run[nt] = vacc;
    }
  }

  // ---- final reduce: sum l,v across q-groups then waves; out = v/l ----
  __syncthreads();  // redA/redB free
#pragma unroll
  for (int nt = 0; nt < 6; ++nt) {
    float ls = l_run[nt], vs = v_run[nt];
    ls += __shfl_xor(ls, 16);
    vs += __shfl_xor(vs, 16);
    ls += __shfl_xor(ls, 32);
    vs += __shfl_xor(vs, 32);
    if (q == 0) {
      redA[w][nt * 16 + r] = ls;
      redB[w][nt * 16 + r] = vs;
    }
  }
  __syncthreads();
  if (tid < 96) {
    float ls = redA[0][tid] + redA[1][tid] + redA[2][tid] + redA[3][tid];
    float vs = redB[0][tid] + redB[1][tid] + redB[2][tid] + redB[3][tid];
    out[(size_t)b * 768 + hd * 96 + tid] = vs / ls;
  }
}

// ---------------- launcher ----------------

extern "C" void kernel_launch(void* const* d_in, const int* in_sizes, int n_in,
                              void* d_out, int out_size, void* d_ws, size_t ws_size,
                              hipStream_t stream) {
  const float* X    = (const float*)d_in[0];
  const float* mask = (const float*)d_in[1];
  const float* P    = (const float*)d_in[2];
  const float* bP   = (const float*)d_in[3];
  const float* W1   = (const float*)d_in[4];
  const float* b1   = (const float*)d_in[5];
  const float* W2   = (const float*)d_in[6];
  const float* b2   = (const float*)d_in[7];
  float* out = (float*)d_out;
  (void)in_sizes; (void)n_in; (void)out_size; (void)ws_size;

  unsigned short* Xbf  = (unsigned short*)d_ws;
  unsigned short* Pbf  = Xbf + N_X;
  unsigned short* W1bf = Pbf + N_P;
  unsigned short* W2bf = W1bf + N_W1;
  unsigned short* Hi   = W2bf + N_W2;

  prep<<<49792, 256, 0, stream>>>(X, P, W1, W2, Xbf, Pbf, W1bf, W2bf);
  gemm_hi<<<3072, 256, 0, stream>>>(Xbf, Pbf, bP, Hi);
  mlp_pool<<<8 * 128, 256, 0, stream>>>(Hi, W1bf, W2bf, b1, b2, mask, out);
}